// Round 11
// baseline (75.550 us; speedup 1.0000x reference)
//
#include <hip/hip_runtime.h>

// SetConv RBF: B=4, NQ=4096, NC=4096, DC=2, DY=8, fp32.
// out[b,q,0:8] = sum_c w(q,c)*y[c] / (den+1e-8); out[b,q,8] = den = sum_c w(q,c)
// w = exp2( (a0q + hc) + a1q*cx + a2q*cy ), negk = -log2(e)/(2*ls^2).
//
// MEASURED LAWS (R1-R10):
//  - dur_us includes 40-47us harness d_ws poison fill + ~10us fixed overhead.
//  - MFMA ladder: R8 ~26us accum -> R9 (fat blocks, LDS B-frag) ~19us.
//  - R10 packed-math NEUTRAL -> loop is stall-bound at 4 waves/SIMD, not
//    VALU-count-bound. Law (R1-R7): time ~ 1/(waves/CU) until pipe saturates.
//  - f16 weights FAIL (range); bf16 OK (fp32 exponent), absmax 0.25 < 0.99.
// R11: GSPLIT 16 -> 2048 blocks = 8 blocks/CU = 8 waves/SIMD (2x TLP),
// launch_bounds(256,8) to cap VGPR<=64. Same hot loop as R10.

#define BB 4
#define NQ 4096
#define NC 4096
#define DY 8
#define NBQ (BB * NQ)           // 16384 queries total

#if __has_builtin(__builtin_amdgcn_exp2f)
#define EXP2F(x) __builtin_amdgcn_exp2f(x)
#else
#define EXP2F(x) exp2f(x)
#endif

typedef short bf16x8 __attribute__((ext_vector_type(8)));
typedef float f32x4  __attribute__((ext_vector_type(4)));
typedef float f32x2  __attribute__((ext_vector_type(2)));

__device__ __forceinline__ short f2bf(float v) {
    return (short)(__builtin_bit_cast(unsigned, v) >> 16);   // truncate
}
__device__ __forceinline__ unsigned fbits(float v) {
    return __builtin_bit_cast(unsigned, v);
}
// pack hi16(w0) -> low half, hi16(w1) -> high half (bf16 pair dword)
__device__ __forceinline__ unsigned bfpair(float w0, float w1) {
#if __has_builtin(__builtin_amdgcn_perm)
    return __builtin_amdgcn_perm(fbits(w1), fbits(w0), 0x07060302u);
#else
    return (fbits(w1) & 0xFFFF0000u) | (fbits(w0) >> 16);
#endif
}

// ---------------- fast path (MFMA) ----------------
#define GSPLIT 16                    // global context split
#define CCHUNK (NC / GSPLIT)         // 256 contexts per block
#define NPAIR (CCHUNK / 2)           // 128 context pairs
#define KSTEPS (CCHUNK / 32)         // 8 mfma k-steps
#define QPB 128                      // queries per block: 4 waves x 2 tiles x 16
#define QB (NBQ / QPB)               // 128 query-blocks
#define JS ((size_t)GSPLIT * NBQ)                     // 262144
#define WS_FLOATS ((size_t)(DY + 1) * GSPLIT * NBQ)   // 2.36M floats = 9.4 MB

// grid = QB*GSPLIT = 2048 blocks of 256 = 8 blocks/CU, 8 waves/SIMD.
__global__ __launch_bounds__(256, 8) void setconv_accum_mfma(
    const float* __restrict__ xq, const float* __restrict__ xc,
    const float* __restrict__ yc, const float* __restrict__ lls,
    float* __restrict__ ws)
{
    __shared__ float4 sxp[NPAIR];                        // (cx0,cx1,cy0,cy1) 2 KB
    __shared__ float2 shp[NPAIR];                        // (hc0,hc1)         1 KB
    __shared__ unsigned short yfrag[CCHUNK / 8][16][8];  // B-frag layout     8 KB

    const int bid  = blockIdx.x;              // 0..2047
    const int gs   = bid & (GSPLIT - 1);
    const int qb   = bid >> 4;                // 0..127
    const int b    = qb >> 5;                 // 32 q-blocks per batch
    const int tid  = threadIdx.x;
    const int lane = tid & 63;
    const int wv   = tid >> 6;
    const int m    = lane & 15;               // A row / D col index
    const int quad = lane >> 4;

    const float L    = lls[0];
    const float negk = -0.72134752044448f * EXP2F(L * -2.8853900817779268f);

    // ---- stage ctx pairs: tid == pair index (tid < 128) ----
    if (tid < NPAIR) {
        const float4* xcp = (const float4*)(((const float2*)xc) + (size_t)b * NC + gs * CCHUNK);
        const float4 v = xcp[tid];            // (cx0,cy0,cx1,cy1)
        sxp[tid] = make_float4(v.x, v.z, v.y, v.w);
        shp[tid] = make_float2(negk * fmaf(v.x, v.x, v.y * v.y),
                               negk * fmaf(v.z, v.z, v.w * v.w));
    }
    // ---- stage Ytilde in B-fragment layout: yfrag[g][n][j] = Y[8g+j][n] ----
    {
        const float4* yp = (const float4*)(yc + ((size_t)b * NC + gs * CCHUNK) * DY);
        const int c = tid;                    // 256 contexts, one per thread
        const float4 A  = yp[2 * c + 0];
        const float4 Bv = yp[2 * c + 1];
        const int g = c >> 3, j = c & 7;
        unsigned short* dst = &yfrag[g][0][j];
        dst[0 * 8] = (unsigned short)f2bf(A.x);
        dst[1 * 8] = (unsigned short)f2bf(A.y);
        dst[2 * 8] = (unsigned short)f2bf(A.z);
        dst[3 * 8] = (unsigned short)f2bf(A.w);
        dst[4 * 8] = (unsigned short)f2bf(Bv.x);
        dst[5 * 8] = (unsigned short)f2bf(Bv.y);
        dst[6 * 8] = (unsigned short)f2bf(Bv.z);
        dst[7 * 8] = (unsigned short)f2bf(Bv.w);
        // cols 8..15: col 8 = 1.0 (density), 9..15 = 0
        unsigned* yf32 = (unsigned*)yfrag;    // u32 idx = g*64 + n*4 + (j>>1)
#pragma unroll
        for (int i = 0; i < 4; ++i) {         // (CCHUNK/8)*32/256 = 4
            const int v = tid + 256 * i;
            const int g2 = v >> 5, r = v & 31; // r = (n-8)*4 + jpair
            yf32[g2 * 64 + 32 + r] = (r < 4) ? 0x3F803F80u : 0u;
        }
    }

    // ---- per-query packed coefficients: wave wv owns tiles 2wv, 2wv+1 ----
    f32x2 A0[2], A1[2], A2[2];
#pragma unroll
    for (int t = 0; t < 2; ++t) {
        const int q = qb * QPB + (wv * 2 + t) * 16 + m;
        const float2 qv = ((const float2*)xq)[q];
        const float a0 = negk * fmaf(qv.x, qv.x, qv.y * qv.y);
        const float a1 = -2.f * negk * qv.x;
        const float a2 = -2.f * negk * qv.y;
        A0[t] = (f32x2){a0, a0};
        A1[t] = (f32x2){a1, a1};
        A2[t] = (f32x2){a2, a2};
    }

    f32x4 acc0 = {0.f, 0.f, 0.f, 0.f};
    f32x4 acc1 = {0.f, 0.f, 0.f, 0.f};

    __syncthreads();

    // ---- hot loop ----
#pragma unroll 2
    for (int s = 0; s < KSTEPS; ++s) {
        const bf16x8 bfrag = *(const bf16x8*)&yfrag[s * 4 + quad][m][0];
        unsigned au0[4], au1[4];
#pragma unroll
        for (int jp = 0; jp < 4; ++jp) {
            const int P = s * 16 + quad * 4 + jp;    // pair index
            const float4 xp = sxp[P];                // (cx0,cx1,cy0,cy1)
            const float2 hp = shp[P];
            const f32x2 cx2 = {xp.x, xp.y};
            const f32x2 cy2 = {xp.z, xp.w};
            const f32x2 hc2 = {hp.x, hp.y};
            f32x2 t0 = __builtin_elementwise_fma(cx2, A1[0], hc2 + A0[0]);
            t0 = __builtin_elementwise_fma(cy2, A2[0], t0);
            f32x2 t1 = __builtin_elementwise_fma(cx2, A1[1], hc2 + A0[1]);
            t1 = __builtin_elementwise_fma(cy2, A2[1], t1);
            au0[jp] = bfpair(EXP2F(t0.x), EXP2F(t0.y));
            au1[jp] = bfpair(EXP2F(t1.x), EXP2F(t1.y));
        }
        const bf16x8 af0 = __builtin_bit_cast(bf16x8, *(uint4*)au0);
        const bf16x8 af1 = __builtin_bit_cast(bf16x8, *(uint4*)au1);
        acc0 = __builtin_amdgcn_mfma_f32_16x16x32_bf16(af0, bfrag, acc0, 0, 0, 0);
        acc1 = __builtin_amdgcn_mfma_f32_16x16x32_bf16(af1, bfrag, acc1, 0, 0, 0);
    }

    // ---- write ws[j][gs][bq]: lane holds D[row=quad*4+r][col=m] ----
    if (m <= 8) {
        const size_t base = (size_t)m * JS + (size_t)gs * NBQ + (size_t)qb * QPB;
#pragma unroll
        for (int r = 0; r < 4; ++r) {
            ws[base + (wv * 2 + 0) * 16 + quad * 4 + r] = acc0[r];
            ws[base + (wv * 2 + 1) * 16 + quad * 4 + r] = acc1[r];
        }
    }
}

// Reduce over GSPLIT=16 + normalize (R5/R6-proven shape). Block: 64 queries,
// 4 groups of 4 splits. Grid = NBQ/64 = 256 blocks.
__global__ __launch_bounds__(256) void setconv_reduce(
    const float* __restrict__ ws, float* __restrict__ out)
{
    __shared__ float part[4][64][DY + 1];
    const int tid  = threadIdx.x;
    const int qi   = tid & 63;
    const int sg   = tid >> 6;
    const int base = blockIdx.x * 64;
    const int bq   = base + qi;

#pragma unroll
    for (int j = 0; j < DY + 1; ++j) {
        float s = 0.f;
#pragma unroll
        for (int k = 0; k < GSPLIT / 4; ++k) {
            const int split = sg * (GSPLIT / 4) + k;
            s += ws[(size_t)j * JS + (size_t)split * NBQ + bq];  // coalesced
        }
        part[sg][qi][j] = s;
    }
    __syncthreads();

    for (int it = tid; it < 64 * (DY + 1); it += 256) {
        const int q2 = it / (DY + 1);
        const int j  = it - q2 * (DY + 1);
        const float den = part[0][q2][DY] + part[1][q2][DY] +
                          part[2][q2][DY] + part[3][q2][DY];
        float v;
        if (j == DY) {
            v = den;
        } else {
            const float s = part[0][q2][j] + part[1][q2][j] +
                            part[2][q2][j] + part[3][q2][j];
            v = s / (den + 1e-8f);
        }
        out[(size_t)base * (DY + 1) + it] = v;    // coalesced
    }
}

// ---------------- fallback path (round-1, known-good): atomics ----------------
#define FSPLIT 8
#define FCCH (NC / FSPLIT)

__global__ __launch_bounds__(256) void setconv_zero(float4* __restrict__ out) {
    out[blockIdx.x * 256 + threadIdx.x] = make_float4(0.f, 0.f, 0.f, 0.f);
}

__global__ __launch_bounds__(256) void setconv_accum_atomic(
    const float* __restrict__ xq, const float* __restrict__ xc,
    const float* __restrict__ yc, const float* __restrict__ lls,
    float* __restrict__ out)
{
    const int bid   = blockIdx.x;
    const int split = bid & (FSPLIT - 1);
    const int qblk  = (bid / FSPLIT) & (NQ / 256 - 1);
    const int b     = bid / (FSPLIT * (NQ / 256));
    const int q     = qblk * 256 + threadIdx.x;

    const float L    = lls[0];
    const float negk = -0.72134752044448f * EXP2F(L * -2.8853900817779268f);

    const float2 qv = ((const float2*)xq)[b * NQ + q];
    const float qx0 = qv.x, qy0 = qv.y;

    float acc[DY], den = 0.f;
#pragma unroll
    for (int j = 0; j < DY; ++j) acc[j] = 0.f;

    const float2* __restrict__ xcp = ((const float2*)xc) + (size_t)b * NC;
    const float4* __restrict__ ycp = ((const float4*)yc) + (size_t)b * NC * 2;

    const int c0 = split * FCCH;
#pragma unroll 4
    for (int c = c0; c < c0 + FCCH; ++c) {
        const float2 cv = xcp[c];
        const float4 y0 = ycp[2 * c + 0];
        const float4 y1 = ycp[2 * c + 1];
        const float dx = qx0 - cv.x;
        const float dy = qy0 - cv.y;
        const float d2 = fmaf(dy, dy, dx * dx);
        const float w  = EXP2F(d2 * negk);
        den += w;
        acc[0] = fmaf(w, y0.x, acc[0]);
        acc[1] = fmaf(w, y0.y, acc[1]);
        acc[2] = fmaf(w, y0.z, acc[2]);
        acc[3] = fmaf(w, y0.w, acc[3]);
        acc[4] = fmaf(w, y1.x, acc[4]);
        acc[5] = fmaf(w, y1.y, acc[5]);
        acc[6] = fmaf(w, y1.z, acc[6]);
        acc[7] = fmaf(w, y1.w, acc[7]);
    }

    float* o = out + (size_t)(b * NQ + q) * (DY + 1);
#pragma unroll
    for (int j = 0; j < DY; ++j) atomicAdd(o + j, acc[j]);
    atomicAdd(o + DY, den);
}

__global__ __launch_bounds__(256) void setconv_norm(float* __restrict__ out) {
    const int q = blockIdx.x * 256 + threadIdx.x;
    float* o = out + (size_t)q * (DY + 1);
    const float inv = 1.0f / (o[DY] + 1e-8f);
#pragma unroll
    for (int j = 0; j < DY; ++j) o[j] *= inv;
}

extern "C" void kernel_launch(void* const* d_in, const int* in_sizes, int n_in,
                              void* d_out, int out_size, void* d_ws, size_t ws_size,
                              hipStream_t stream) {
    const float* xq  = (const float*)d_in[0];  // (4,4096,2)
    const float* xc  = (const float*)d_in[1];  // (4,4096,2)
    const float* yc  = (const float*)d_in[2];  // (4,4096,8)
    const float* lls = (const float*)d_in[3];  // scalar
    float* out = (float*)d_out;                // (4,4096,9)

    if (ws_size >= WS_FLOATS * sizeof(float)) {
        float* ws = (float*)d_ws;
        setconv_accum_mfma<<<QB * GSPLIT, 256, 0, stream>>>(xq, xc, yc, lls, ws);
        setconv_reduce<<<NBQ / 64, 256, 0, stream>>>(ws, out);
    } else {
        setconv_zero<<<(NBQ * (DY + 1)) / 1024, 256, 0, stream>>>((float4*)out);
        setconv_accum_atomic<<<BB * (NQ / 256) * FSPLIT, 256, 0, stream>>>(xq, xc, yc, lls, out);
        setconv_norm<<<NBQ / 256, 256, 0, stream>>>(out);
    }
}

// Round 12
// 74.844 us; speedup vs baseline: 1.0094x; 1.0094x over previous
//
#include <hip/hip_runtime.h>

// SetConv RBF: B=4, NQ=4096, NC=4096, DC=2, DY=8, fp32.
// out[b,q,0:8] = sum_c w(q,c)*y[c] / (den+1e-8); out[b,q,8] = den = sum_c w(q,c)
// w = exp2( (a0q + hc) + a1q*cx + a2q*cy ), negk = -log2(e)/(2*ls^2).
//
// MEASURED LAWS (R1-R11):
//  - dur_us includes 40-47us harness d_ws poison fill + ~10us fixed overhead.
//  - MFMA ladder: R8 ~28us accum -> R9/R10 ~19.5us. R10 packed-math NEUTRAL;
//    R11 2x blocks NEUTRAL -> not VALU-issue-bound, not TLP-bound. Per-CU
//    pipe math at 183cyc/kstep: DS~84, VALU~28, trans~32 -> all pipes <50%
//    busy => per-wave dependency-stall-bound. Fix: more indep work/kstep.
//  - f16 weights FAIL (range); bf16 OK (fp32 exponent), absmax 0.25 < 0.99.
// R12: 4 query-tiles per wave (QPB=256): ctx broadcast reads amortized over
// 4 tiles (DS/pair halved), 4 indep MFMA+exp chains per kstep, half the
// kstep count. 512 blocks, 8 waves/CU, launch_bounds(256,4).

#define BB 4
#define NQ 4096
#define NC 4096
#define DY 8
#define NBQ (BB * NQ)           // 16384 queries total

#if __has_builtin(__builtin_amdgcn_exp2f)
#define EXP2F(x) __builtin_amdgcn_exp2f(x)
#else
#define EXP2F(x) exp2f(x)
#endif

typedef short bf16x8 __attribute__((ext_vector_type(8)));
typedef float f32x4  __attribute__((ext_vector_type(4)));

__device__ __forceinline__ short f2bf(float v) {
    return (short)(__builtin_bit_cast(unsigned, v) >> 16);   // truncate
}
__device__ __forceinline__ unsigned fbits(float v) {
    return __builtin_bit_cast(unsigned, v);
}
// pack hi16(w0) -> low half, hi16(w1) -> high half (bf16 pair dword)
__device__ __forceinline__ unsigned bfpair(float w0, float w1) {
#if __has_builtin(__builtin_amdgcn_perm)
    return __builtin_amdgcn_perm(fbits(w1), fbits(w0), 0x07060302u);
#else
    return (fbits(w1) & 0xFFFF0000u) | (fbits(w0) >> 16);
#endif
}

// ---------------- fast path (MFMA) ----------------
#define GSPLIT 8                     // global context split
#define CCHUNK (NC / GSPLIT)         // 512 contexts per block
#define NPAIR (CCHUNK / 2)           // 256 context pairs
#define KSTEPS (CCHUNK / 32)         // 16 mfma k-steps
#define NT 4                         // query tiles per wave
#define QPB 256                      // queries per block: 4 waves x 4 tiles x 16
#define QB (NBQ / QPB)               // 64 query-blocks
#define JS ((size_t)GSPLIT * NBQ)                     // 131072
#define WS_FLOATS ((size_t)(DY + 1) * GSPLIT * NBQ)   // 1.18M floats = 4.7 MB

// grid = QB*GSPLIT = 512 blocks of 256 = 2 blocks/CU, 8 waves/CU.
__global__ __launch_bounds__(256, 4) void setconv_accum_mfma(
    const float* __restrict__ xq, const float* __restrict__ xc,
    const float* __restrict__ yc, const float* __restrict__ lls,
    float* __restrict__ ws)
{
    __shared__ float4 sxp[NPAIR];                        // (cx0,cx1,cy0,cy1) 4 KB
    __shared__ float2 shp[NPAIR];                        // (hc0,hc1)         2 KB
    __shared__ unsigned short yfrag[CCHUNK / 8][16][8];  // B-frag layout    16 KB

    const int bid  = blockIdx.x;              // 0..511
    const int gs   = bid & (GSPLIT - 1);
    const int qb   = bid >> 3;                // 0..63
    const int b    = qb >> 4;                 // 16 q-blocks per batch
    const int tid  = threadIdx.x;
    const int lane = tid & 63;
    const int wv   = tid >> 6;
    const int m    = lane & 15;               // A row / D col index
    const int quad = lane >> 4;

    const float L    = lls[0];
    const float negk = -0.72134752044448f * EXP2F(L * -2.8853900817779268f);

    // ---- stage ctx pairs: tid == pair index (256 pairs) ----
    {
        const float4* xcp = (const float4*)(((const float2*)xc) + (size_t)b * NC + gs * CCHUNK);
        const float4 v = xcp[tid];            // (cx0,cy0,cx1,cy1)
        sxp[tid] = make_float4(v.x, v.z, v.y, v.w);
        shp[tid] = make_float2(negk * fmaf(v.x, v.x, v.y * v.y),
                               negk * fmaf(v.z, v.z, v.w * v.w));
    }
    // ---- stage Ytilde in B-fragment layout: yfrag[g][n][j] = Y[8g+j][n] ----
    {
        const float4* yp = (const float4*)(yc + ((size_t)b * NC + gs * CCHUNK) * DY);
#pragma unroll
        for (int i = 0; i < 2; ++i) {
            const int c = tid + 256 * i;
            const float4 A  = yp[2 * c + 0];
            const float4 Bv = yp[2 * c + 1];
            const int g = c >> 3, j = c & 7;
            unsigned short* dst = &yfrag[g][0][j];
            dst[0 * 8] = (unsigned short)f2bf(A.x);
            dst[1 * 8] = (unsigned short)f2bf(A.y);
            dst[2 * 8] = (unsigned short)f2bf(A.z);
            dst[3 * 8] = (unsigned short)f2bf(A.w);
            dst[4 * 8] = (unsigned short)f2bf(Bv.x);
            dst[5 * 8] = (unsigned short)f2bf(Bv.y);
            dst[6 * 8] = (unsigned short)f2bf(Bv.z);
            dst[7 * 8] = (unsigned short)f2bf(Bv.w);
        }
        // cols 8..15: col 8 = 1.0 (density), 9..15 = 0
        unsigned* yf32 = (unsigned*)yfrag;    // u32 idx = g*64 + n*4 + (j>>1)
#pragma unroll
        for (int i = 0; i < 8; ++i) {         // (CCHUNK/8)*32/256 = 8
            const int v = tid + 256 * i;
            const int g2 = v >> 5, r = v & 31; // r = (n-8)*4 + jpair
            yf32[g2 * 64 + 32 + r] = (r < 4) ? 0x3F803F80u : 0u;
        }
    }

    // ---- per-query coefficients: wave wv owns tiles wv*4 .. wv*4+3 ----
    float a0[NT], a1[NT], a2[NT];
#pragma unroll
    for (int t = 0; t < NT; ++t) {
        const int q = qb * QPB + (wv * NT + t) * 16 + m;
        const float2 qv = ((const float2*)xq)[q];
        a0[t] = negk * fmaf(qv.x, qv.x, qv.y * qv.y);
        a1[t] = -2.f * negk * qv.x;
        a2[t] = -2.f * negk * qv.y;
    }

    f32x4 acc[NT];
#pragma unroll
    for (int t = 0; t < NT; ++t) acc[t] = (f32x4){0.f, 0.f, 0.f, 0.f};

    __syncthreads();

    // ---- hot loop: ctx reads hoisted, shared by 4 tiles ----
#pragma unroll 2
    for (int s = 0; s < KSTEPS; ++s) {
        const int pb = s * 16 + quad * 4;
        const bf16x8 bfrag = *(const bf16x8*)&yfrag[s * 4 + quad][m][0];
        const float4 xpA = sxp[pb + 0]; const float2 hpA = shp[pb + 0];
        const float4 xpB = sxp[pb + 1]; const float2 hpB = shp[pb + 1];
        const float4 xpC = sxp[pb + 2]; const float2 hpC = shp[pb + 2];
        const float4 xpD = sxp[pb + 3]; const float2 hpD = shp[pb + 3];
#pragma unroll
        for (int t = 0; t < NT; ++t) {
            uint4 au;
            {   // pair A: ctx0=(xpA.x,xpA.z), ctx1=(xpA.y,xpA.w)
                float u = fmaf(a2[t], xpA.z, fmaf(a1[t], xpA.x, a0[t] + hpA.x));
                float v = fmaf(a2[t], xpA.w, fmaf(a1[t], xpA.y, a0[t] + hpA.y));
                au.x = bfpair(EXP2F(u), EXP2F(v));
            }
            {
                float u = fmaf(a2[t], xpB.z, fmaf(a1[t], xpB.x, a0[t] + hpB.x));
                float v = fmaf(a2[t], xpB.w, fmaf(a1[t], xpB.y, a0[t] + hpB.y));
                au.y = bfpair(EXP2F(u), EXP2F(v));
            }
            {
                float u = fmaf(a2[t], xpC.z, fmaf(a1[t], xpC.x, a0[t] + hpC.x));
                float v = fmaf(a2[t], xpC.w, fmaf(a1[t], xpC.y, a0[t] + hpC.y));
                au.z = bfpair(EXP2F(u), EXP2F(v));
            }
            {
                float u = fmaf(a2[t], xpD.z, fmaf(a1[t], xpD.x, a0[t] + hpD.x));
                float v = fmaf(a2[t], xpD.w, fmaf(a1[t], xpD.y, a0[t] + hpD.y));
                au.w = bfpair(EXP2F(u), EXP2F(v));
            }
            const bf16x8 af = __builtin_bit_cast(bf16x8, au);
            acc[t] = __builtin_amdgcn_mfma_f32_16x16x32_bf16(af, bfrag, acc[t], 0, 0, 0);
        }
    }

    // ---- write ws[j][gs][bq]: lane holds D[row=quad*4+r][col=m] ----
    if (m <= 8) {
        const size_t base = (size_t)m * JS + (size_t)gs * NBQ + (size_t)qb * QPB;
#pragma unroll
        for (int t = 0; t < NT; ++t) {
#pragma unroll
            for (int r = 0; r < 4; ++r)
                ws[base + (wv * NT + t) * 16 + quad * 4 + r] = acc[t][r];
        }
    }
}

// Reduce over GSPLIT=8 + normalize (R4/R8/R9-proven). Block: 64 queries,
// 4 groups of 2 splits. Grid = NBQ/64 = 256 blocks.
__global__ __launch_bounds__(256) void setconv_reduce(
    const float* __restrict__ ws, float* __restrict__ out)
{
    __shared__ float part[4][64][DY + 1];
    const int tid  = threadIdx.x;
    const int qi   = tid & 63;
    const int sg   = tid >> 6;
    const int base = blockIdx.x * 64;
    const int bq   = base + qi;

#pragma unroll
    for (int j = 0; j < DY + 1; ++j) {
        float s = 0.f;
#pragma unroll
        for (int k = 0; k < GSPLIT / 4; ++k) {
            const int split = sg * (GSPLIT / 4) + k;
            s += ws[(size_t)j * JS + (size_t)split * NBQ + bq];  // coalesced
        }
        part[sg][qi][j] = s;
    }
    __syncthreads();

    for (int it = tid; it < 64 * (DY + 1); it += 256) {
        const int q2 = it / (DY + 1);
        const int j  = it - q2 * (DY + 1);
        const float den = part[0][q2][DY] + part[1][q2][DY] +
                          part[2][q2][DY] + part[3][q2][DY];
        float v;
        if (j == DY) {
            v = den;
        } else {
            const float s = part[0][q2][j] + part[1][q2][j] +
                            part[2][q2][j] + part[3][q2][j];
            v = s / (den + 1e-8f);
        }
        out[(size_t)base * (DY + 1) + it] = v;    // coalesced
    }
}

// ---------------- fallback path (round-1, known-good): atomics ----------------
#define FSPLIT 8
#define FCCH (NC / FSPLIT)

__global__ __launch_bounds__(256) void setconv_zero(float4* __restrict__ out) {
    out[blockIdx.x * 256 + threadIdx.x] = make_float4(0.f, 0.f, 0.f, 0.f);
}

__global__ __launch_bounds__(256) void setconv_accum_atomic(
    const float* __restrict__ xq, const float* __restrict__ xc,
    const float* __restrict__ yc, const float* __restrict__ lls,
    float* __restrict__ out)
{
    const int bid   = blockIdx.x;
    const int split = bid & (FSPLIT - 1);
    const int qblk  = (bid / FSPLIT) & (NQ / 256 - 1);
    const int b     = bid / (FSPLIT * (NQ / 256));
    const int q     = qblk * 256 + threadIdx.x;

    const float L    = lls[0];
    const float negk = -0.72134752044448f * EXP2F(L * -2.8853900817779268f);

    const float2 qv = ((const float2*)xq)[b * NQ + q];
    const float qx0 = qv.x, qy0 = qv.y;

    float acc[DY], den = 0.f;
#pragma unroll
    for (int j = 0; j < DY; ++j) acc[j] = 0.f;

    const float2* __restrict__ xcp = ((const float2*)xc) + (size_t)b * NC;
    const float4* __restrict__ ycp = ((const float4*)yc) + (size_t)b * NC * 2;

    const int c0 = split * FCCH;
#pragma unroll 4
    for (int c = c0; c < c0 + FCCH; ++c) {
        const float2 cv = xcp[c];
        const float4 y0 = ycp[2 * c + 0];
        const float4 y1 = ycp[2 * c + 1];
        const float dx = qx0 - cv.x;
        const float dy = qy0 - cv.y;
        const float d2 = fmaf(dy, dy, dx * dx);
        const float w  = EXP2F(d2 * negk);
        den += w;
        acc[0] = fmaf(w, y0.x, acc[0]);
        acc[1] = fmaf(w, y0.y, acc[1]);
        acc[2] = fmaf(w, y0.z, acc[2]);
        acc[3] = fmaf(w, y0.w, acc[3]);
        acc[4] = fmaf(w, y1.x, acc[4]);
        acc[5] = fmaf(w, y1.y, acc[5]);
        acc[6] = fmaf(w, y1.z, acc[6]);
        acc[7] = fmaf(w, y1.w, acc[7]);
    }

    float* o = out + (size_t)(b * NQ + q) * (DY + 1);
#pragma unroll
    for (int j = 0; j < DY; ++j) atomicAdd(o + j, acc[j]);
    atomicAdd(o + DY, den);
}

__global__ __launch_bounds__(256) void setconv_norm(float* __restrict__ out) {
    const int q = blockIdx.x * 256 + threadIdx.x;
    float* o = out + (size_t)q * (DY + 1);
    const float inv = 1.0f / (o[DY] + 1e-8f);
#pragma unroll
    for (int j = 0; j < DY; ++j) o[j] *= inv;
}

extern "C" void kernel_launch(void* const* d_in, const int* in_sizes, int n_in,
                              void* d_out, int out_size, void* d_ws, size_t ws_size,
                              hipStream_t stream) {
    const float* xq  = (const float*)d_in[0];  // (4,4096,2)
    const float* xc  = (const float*)d_in[1];  // (4,4096,2)
    const float* yc  = (const float*)d_in[2];  // (4,4096,8)
    const float* lls = (const float*)d_in[3];  // scalar
    float* out = (float*)d_out;                // (4,4096,9)

    if (ws_size >= WS_FLOATS * sizeof(float)) {
        float* ws = (float*)d_ws;
        setconv_accum_mfma<<<QB * GSPLIT, 256, 0, stream>>>(xq, xc, yc, lls, ws);
        setconv_reduce<<<NBQ / 64, 256, 0, stream>>>(ws, out);
    } else {
        setconv_zero<<<(NBQ * (DY + 1)) / 1024, 256, 0, stream>>>((float4*)out);
        setconv_accum_atomic<<<BB * (NQ / 256) * FSPLIT, 256, 0, stream>>>(xq, xc, yc, lls, out);
        setconv_norm<<<NBQ / 256, 256, 0, stream>>>(out);
    }
}